// Round 10
// baseline (126.811 us; speedup 1.0000x reference)
//
#include <hip/hip_runtime.h>
#include <math.h>

#define B_ 2
#define S_ 2048
#define D_ 512
#define NB_ 64
#define NH_ 6
#define ROWS (B_*S_)           // 4096
#define SCALE 0.044194173824159216f   // 1/sqrt(512)

typedef float f32x4 __attribute__((ext_vector_type(4)));
typedef __bf16 bf16v8 __attribute__((ext_vector_type(8)));
typedef short s16x8 __attribute__((ext_vector_type(8)));
typedef unsigned short u16x4 __attribute__((ext_vector_type(4)));

__device__ __forceinline__ float b2f(unsigned short u) {
    unsigned int v = (unsigned int)u << 16;
    float f; __builtin_memcpy(&f, &v, 4); return f;
}
__device__ __forceinline__ unsigned short f2b(float f) {
    unsigned int v; __builtin_memcpy(&v, &f, 4);
    v += 0x7fffu + ((v >> 16) & 1u);      // RNE
    return (unsigned short)(v >> 16);
}

#define GLOAD16(g, l) __builtin_amdgcn_global_load_lds( \
    (const __attribute__((address_space(1))) unsigned int*)(g), \
    (__attribute__((address_space(3))) unsigned int*)(uintptr_t)(l), 16, 0, 0)

// ---------------- prep: zeros + f32->bf16 converts ----------------
__global__ void prep_kernel(
    const float* __restrict__ x, unsigned short* __restrict__ xh,
    const float* __restrict__ Wq, const float* __restrict__ Wv,
    unsigned short* __restrict__ Wqvh,
    float* __restrict__ Mrow, int* __restrict__ cnt, float* __restrict__ sumVall)
{
    int t = blockIdx.x * 256 + threadIdx.x;
    int stride = gridDim.x * 256;
    for (int i = t; i < ROWS * D_ / 4; i += stride) {
        float4 f = ((const float4*)x)[i];
        u16x4 u = { f2b(f.x), f2b(f.y), f2b(f.z), f2b(f.w) };
        ((u16x4*)xh)[i] = u;
    }
    for (int i = t; i < D_ * D_ / 4; i += stride) {
        float4 f = ((const float4*)Wq)[i];
        u16x4 u = { f2b(f.x), f2b(f.y), f2b(f.z), f2b(f.w) };
        ((u16x4*)Wqvh)[i] = u;
        float4 g = ((const float4*)Wv)[i];
        u16x4 w = { f2b(g.x), f2b(g.y), f2b(g.z), f2b(g.w) };
        ((u16x4*)(Wqvh + (size_t)D_ * D_))[i] = w;
    }
    for (int i = t; i < ROWS; i += stride) Mrow[i] = 0.f;
    for (int i = t; i < B_ * NB_; i += stride) cnt[i] = 0;
    for (int i = t; i < B_ * D_; i += stride) sumVall[i] = 0.f;
}

// ---------------- fused q|v projection, tile 128x64x64, N=1024 ----------------
__global__ __launch_bounds__(256) void mfma_proj(
    const unsigned short* __restrict__ A, const unsigned short* __restrict__ B,
    const float* __restrict__ bq, const float* __restrict__ bv,
    float* __restrict__ MrowRaw, unsigned short* __restrict__ qh,
    float* __restrict__ v)
{
    __shared__ unsigned short Als[128 * 64];   // 16KB
    __shared__ unsigned short Bls[64 * 64];    // 8KB
    const int K = D_;
    int tid = threadIdx.x;
    int w = tid >> 6, l = tid & 63;
    int wr = w >> 1, wc = w & 1;

    int gx = gridDim.x;
    int nwg = gx * gridDim.y;
    int lin = blockIdx.y * gx + blockIdx.x;
    int qq = nwg >> 3;
    int wg = (lin & 7) * qq + (lin >> 3);
    int m0 = (wg / gx) * 128, n0 = (wg % gx) * 64;

    const unsigned short* asrc[4];
    #pragma unroll
    for (int j = 0; j < 4; ++j) {
        int chunk = w * 4 + j;
        int r = chunk * 8 + (l >> 3);
        asrc[j] = A + (size_t)(m0 + r) * K + ((l & 7) ^ (l >> 3)) * 8;
    }
    const unsigned short* bsrc[2];
    #pragma unroll
    for (int j = 0; j < 2; ++j) {
        int chunk = w * 2 + j;
        int r = n0 + chunk * 8 + (l >> 3);
        bsrc[j] = B + (size_t)r * K + ((l & 7) ^ (l >> 3)) * 8;
    }

    f32x4 acc[4][2] = {};
    int rl = l & 15, hi = l >> 4;

    for (int k0 = 0; k0 < K; k0 += 64) {
        #pragma unroll
        for (int j = 0; j < 4; ++j) GLOAD16(asrc[j] + k0, Als + (w * 4 + j) * 512);
        #pragma unroll
        for (int j = 0; j < 2; ++j) GLOAD16(bsrc[j] + k0, Bls + (w * 2 + j) * 512);
        __syncthreads();
        bf16v8 af[4][2], bfr[2][2];
        const char* Ab = (const char*)Als;
        const char* Bb = (const char*)Bls;
        #pragma unroll
        for (int kk = 0; kk < 2; ++kk) {
            int kb = kk * 64 + hi * 16;
            #pragma unroll
            for (int f = 0; f < 4; ++f) {
                int ra = wr * 64 + f * 16 + rl;
                af[f][kk] = *(const bf16v8*)(Ab + ra * 128 + (kb ^ ((ra & 7) << 4)));
            }
            #pragma unroll
            for (int f = 0; f < 2; ++f) {
                int rb = wc * 32 + f * 16 + rl;
                bfr[f][kk] = *(const bf16v8*)(Bb + rb * 128 + (kb ^ ((rb & 7) << 4)));
            }
        }
        #pragma unroll
        for (int fm = 0; fm < 4; ++fm)
            #pragma unroll
            for (int fn = 0; fn < 2; ++fn)
                #pragma unroll
                for (int kk = 0; kk < 2; ++kk)
                    acc[fm][fn] = __builtin_amdgcn_mfma_f32_16x16x32_bf16(
                        af[fm][kk], bfr[fn][kk], acc[fm][fn], 0, 0, 0);
        __syncthreads();
    }

    int colBase = n0 + wc * 32;
    if (colBase < D_) {
        #pragma unroll
        for (int fm = 0; fm < 4; ++fm) {
            float p[4] = {0.f, 0.f, 0.f, 0.f};
            #pragma unroll
            for (int fn = 0; fn < 2; ++fn) {
                int col = colBase + fn * 16 + rl;
                float bs = bq[col];
                #pragma unroll
                for (int r = 0; r < 4; ++r) {
                    int row = m0 + wr * 64 + fm * 16 + hi * 4 + r;
                    float cv = acc[fm][fn][r] + bs;
                    unsigned short h = f2b(cv);
                    qh[(size_t)row * D_ + col] = h;
                    float qb = b2f(h);
                    p[r] = fmaf(qb, qb, p[r]);
                }
            }
            #pragma unroll
            for (int mask = 1; mask < 16; mask <<= 1)
                #pragma unroll
                for (int r = 0; r < 4; ++r) p[r] += __shfl_xor(p[r], mask);
            if (rl == 0) {
                #pragma unroll
                for (int r = 0; r < 4; ++r) {
                    int row = m0 + wr * 64 + fm * 16 + hi * 4 + r;
                    atomicAdd(&MrowRaw[row], p[r]);
                }
            }
        }
    } else {
        #pragma unroll
        for (int fm = 0; fm < 4; ++fm)
            #pragma unroll
            for (int fn = 0; fn < 2; ++fn) {
                int col = colBase + fn * 16 + rl - D_;
                float bs = bv[col];
                #pragma unroll
                for (int r = 0; r < 4; ++r) {
                    int row = m0 + wr * 64 + fm * 16 + hi * 4 + r;
                    v[(size_t)row * D_ + col] = acc[fm][fn][r] + bs;
                }
            }
    }
}

// ---------------- QK^T, 128x128x64 tile, exp epilogue, perm on B ----------------
__global__ __launch_bounds__(256) void mfma_qk(
    const unsigned short* __restrict__ qh, const int* __restrict__ prm,
    const float* __restrict__ Mrow, unsigned short* __restrict__ Eh)
{
    __shared__ unsigned short Als[128 * 64];   // 16KB
    __shared__ unsigned short Bls[128 * 64];   // 16KB
    const int K = D_;
    int tid = threadIdx.x;
    int w = tid >> 6, l = tid & 63;
    int wr = w >> 1, wc = w & 1;
    int zb = blockIdx.z;
    const unsigned short* A = qh + (size_t)zb * S_ * D_;
    prm += (size_t)zb * S_;
    const float* Mb = Mrow + (size_t)zb * S_;
    unsigned short* Eb = Eh + (size_t)zb * S_ * S_;

    int gx = gridDim.x;
    int nwg = gx * gridDim.y;
    int lin = blockIdx.y * gx + blockIdx.x;
    int qq = nwg >> 3;
    int wg = (lin & 7) * qq + (lin >> 3);
    int m0 = (wg / gx) * 128, n0 = (wg % gx) * 128;

    const unsigned short* asrc[4];
    const unsigned short* bsrc[4];
    #pragma unroll
    for (int j = 0; j < 4; ++j) {
        int chunk = w * 4 + j;
        int r = chunk * 8 + (l >> 3);
        int c = ((l & 7) ^ (l >> 3)) * 8;
        asrc[j] = A + (size_t)(m0 + r) * K + c;
        bsrc[j] = A + (size_t)prm[n0 + r] * K + c;
    }

    f32x4 acc[4][4] = {};
    int rl = l & 15, hi = l >> 4;

    for (int k0 = 0; k0 < K; k0 += 64) {
        #pragma unroll
        for (int j = 0; j < 4; ++j) GLOAD16(asrc[j] + k0, Als + (w * 4 + j) * 512);
        #pragma unroll
        for (int j = 0; j < 4; ++j) GLOAD16(bsrc[j] + k0, Bls + (w * 4 + j) * 512);
        __syncthreads();
        bf16v8 af[4][2], bfr[4][2];
        const char* Ab = (const char*)Als;
        const char* Bb = (const char*)Bls;
        #pragma unroll
        for (int kk = 0; kk < 2; ++kk) {
            int kb = kk * 64 + hi * 16;
            #pragma unroll
            for (int f = 0; f < 4; ++f) {
                int ra = wr * 64 + f * 16 + rl;
                af[f][kk] = *(const bf16v8*)(Ab + ra * 128 + (kb ^ ((ra & 7) << 4)));
                int rb = wc * 64 + f * 16 + rl;
                bfr[f][kk] = *(const bf16v8*)(Bb + rb * 128 + (kb ^ ((rb & 7) << 4)));
            }
        }
        #pragma unroll
        for (int fm = 0; fm < 4; ++fm)
            #pragma unroll
            for (int fn = 0; fn < 4; ++fn)
                #pragma unroll
                for (int kk = 0; kk < 2; ++kk)
                    acc[fm][fn] = __builtin_amdgcn_mfma_f32_16x16x32_bf16(
                        af[fm][kk], bfr[fn][kk], acc[fm][fn], 0, 0, 0);
        __syncthreads();
    }

    #pragma unroll
    for (int fm = 0; fm < 4; ++fm) {
        #pragma unroll
        for (int r = 0; r < 4; ++r) {
            int row = m0 + wr * 64 + fm * 16 + hi * 4 + r;
            float m = Mb[row];
            #pragma unroll
            for (int fn = 0; fn < 4; ++fn) {
                int col = n0 + wc * 64 + fn * 16 + rl;
                float ev = __expf(fmaf(acc[fm][fn][r], SCALE, -m));
                Eb[(size_t)row * S_ + col] = f2b(ev);
            }
        }
    }
}

// ---------------- PV GEMM: out = E' vT^T + rowterm. tile 64x64, BK=128, 4 waves ----------------
// grid (8, 32, B): m-panel-grouped XCD mapping
__global__ __launch_bounds__(256) void mfma_pv64(
    const unsigned short* __restrict__ Eh, const unsigned short* __restrict__ vT,
    const float* __restrict__ sumVall, const float* __restrict__ sumVb,
    const int* __restrict__ bucket, float* __restrict__ out)
{
    __shared__ unsigned short Als[64 * 128];   // 16KB
    __shared__ unsigned short Bls[64 * 128];   // 16KB
    int tid = threadIdx.x, w = tid >> 6, l = tid & 63;
    int wr = w >> 1, wc = w & 1, rl = l & 15, hi = l >> 4;
    int zb = blockIdx.z;
    const unsigned short* A  = Eh + (size_t)zb * S_ * S_;
    const unsigned short* Bv = vT + (size_t)zb * D_ * S_;
    const float* sva = sumVall + (size_t)zb * D_;
    const float* svb = sumVb + (size_t)zb * NB_ * D_;
    const int* bkt = bucket + (size_t)zb * S_;
    float* outb = out + (size_t)zb * S_ * D_;

    int lin = blockIdx.y * 8 + blockIdx.x;    // 0..255
    int xcd = lin & 7, rest = lin >> 3;
    int m0 = (((rest >> 3) << 3) | xcd) * 64;
    int n0 = (rest & 7) * 64;

    // staging: tile 64 rows x 128 bf16 (256B/row), 16 chunks of 1KB (4 rows each)
    // lane l in chunk ch: row = ch*4 + (l>>4), 16B-unit col = (l&15) ^ (row&7)
    const unsigned short* asrc[4];
    const unsigned short* bsrc[4];
    #pragma unroll
    for (int j = 0; j < 4; ++j) {
        int ch = w * 4 + j;
        int r = ch * 4 + (l >> 4);
        int c16 = (l & 15) ^ (r & 7);
        asrc[j] = A  + (size_t)(m0 + r) * S_ + c16 * 8;
        bsrc[j] = Bv + (size_t)(n0 + r) * S_ + c16 * 8;
    }

    f32x4 acc[2][2] = {};
    for (int k0 = 0; k0 < S_; k0 += 128) {
        #pragma unroll
        for (int j = 0; j < 4; ++j) GLOAD16(asrc[j] + k0, Als + (w * 4 + j) * 512);
        #pragma unroll
        for (int j = 0; j < 4; ++j) GLOAD16(bsrc[j] + k0, Bls + (w * 4 + j) * 512);
        __syncthreads();
        const char* Ab = (const char*)Als;
        const char* Bb = (const char*)Bls;
        #pragma unroll
        for (int ks = 0; ks < 4; ++ks) {
            int kb = ks * 64 + hi * 16;
            bf16v8 af[2], bfr[2];
            #pragma unroll
            for (int f = 0; f < 2; ++f) {
                int ra = wr * 32 + f * 16 + rl;
                af[f] = *(const bf16v8*)(Ab + ra * 256 + (kb ^ ((ra & 7) << 4)));
                int rb = wc * 32 + f * 16 + rl;
                bfr[f] = *(const bf16v8*)(Bb + rb * 256 + (kb ^ ((rb & 7) << 4)));
            }
            #pragma unroll
            for (int fm = 0; fm < 2; ++fm)
                #pragma unroll
                for (int fn = 0; fn < 2; ++fn)
                    acc[fm][fn] = __builtin_amdgcn_mfma_f32_16x16x32_bf16(
                        af[fm], bfr[fn], acc[fm][fn], 0, 0, 0);
        }
        __syncthreads();
    }
    const float invS = 1.0f / (float)S_;
    #pragma unroll
    for (int fm = 0; fm < 2; ++fm)
        #pragma unroll
        for (int fn = 0; fn < 2; ++fn) {
            int col = n0 + wc * 32 + fn * 16 + rl;
            float sa = sva[col];
            #pragma unroll
            for (int r = 0; r < 4; ++r) {
                int row = m0 + wr * 32 + fm * 16 + hi * 4 + r;
                int bm = bkt[row];
                outb[(size_t)row * D_ + col] =
                    acc[fm][fn][r] + (sa - svb[(size_t)bm * D_ + col]) * invS;
            }
        }
}

// ---------------- merged: transpose_v (blocks 0..2047) + sumv2 (blocks 2048..2303) ----------------
__global__ __launch_bounds__(256) void vprep_kernel(
    const float* __restrict__ v, const int* __restrict__ perm,
    unsigned short* __restrict__ vT,
    const int* __restrict__ cnt, const int* __restrict__ idxl,
    float* __restrict__ sumVb, float* __restrict__ sumVall)
{
    int bid = blockIdx.x;
    if (bid < 2048) {
        __shared__ float tl[32][33];
        int b = bid >> 10;
        int r = bid & 1023;
        int d0 = (r & 15) * 32, s0 = (r >> 4) * 32;
        int tx = threadIdx.x & 31, ty = threadIdx.x >> 5;
        const float* vb = v + (size_t)b * S_ * D_;
        const int* pm = perm + (size_t)b * S_;
        #pragma unroll
        for (int i = 0; i < 4; ++i)
            tl[ty + i * 8][tx] = vb[(size_t)pm[s0 + ty + i * 8] * D_ + d0 + tx];
        __syncthreads();
        unsigned short* vt = vT + (size_t)b * D_ * S_;
        #pragma unroll
        for (int i = 0; i < 4; ++i)
            vt[(size_t)(d0 + ty + i * 8) * S_ + s0 + tx] = f2b(tl[tx][ty + i * 8]);
    } else {
        int sid = bid - 2048;
        int j = sid & 63, b = (sid >> 6) & 1, dblk = sid >> 7;
        int d = dblk * 256 + threadIdx.x;
        int n = cnt[b * NB_ + j];
        const int* lst = idxl + ((size_t)(b * NB_ + j)) * S_;
        const float* vb = v + (size_t)b * S_ * D_;
        float acc = 0.f;
        for (int k = 0; k < n; ++k)
            acc += vb[(size_t)lst[k] * D_ + d];
        sumVb[((size_t)b * NB_ + j) * D_ + d] = acc;
        atomicAdd(&sumVall[b * D_ + d], acc);
    }
}

// ---------------- buckets from qh + hist; finalize Mrow ----------------
__global__ __launch_bounds__(64) void bucket_kernel(
    const unsigned short* __restrict__ qh, const float* __restrict__ H,
    int* __restrict__ bucket, float* __restrict__ Mrow,
    int* __restrict__ cnt, int* __restrict__ idxl)
{
    int row = blockIdx.x;
    int lane = threadIdx.x;
    const unsigned short* qr = qh + (size_t)row * D_;
    float proj[NH_] = {};
    s16x8 qv8 = *(const s16x8*)(qr + lane * 8);
    #pragma unroll
    for (int i = 0; i < 8; ++i) {
        float qv = b2f((unsigned short)qv8[i]);
        int d = lane * 8 + i;
        #pragma unroll
        for (int n = 0; n < NH_; ++n)
            proj[n] = fmaf(qv, H[d * NH_ + n], proj[n]);
    }
    #pragma unroll
    for (int off = 32; off; off >>= 1) {
        #pragma unroll
        for (int n = 0; n < NH_; ++n) proj[n] += __shfl_down(proj[n], off);
    }
    if (lane == 0) {
        int bk = 0;
        #pragma unroll
        for (int n = 0; n < NH_; ++n) {
            float p = proj[n] + H[D_ * NH_ + n];
            if (p >= 0.f) bk |= (1 << n);
        }
        bucket[row] = bk;
        Mrow[row] = Mrow[row] * SCALE;
        int b = row >> 11, s = row & (S_ - 1);
        int pos = atomicAdd(&cnt[b * NB_ + bk], 1);
        idxl[((size_t)(b * NB_ + bk)) * S_ + pos] = s;
    }
}

// ---------------- prefix sum + cooperative perm/p2b build (one block per batch) ----------------
__global__ __launch_bounds__(64) void permprefix_kernel(
    const int* __restrict__ cnt, const int* __restrict__ idxl,
    int* __restrict__ off, int* __restrict__ perm, int* __restrict__ p2b)
{
    int b = blockIdx.x;
    int j = threadIdx.x;
    __shared__ int offs[NB_ + 1];
    int c = cnt[b * NB_ + j];
    int x = c;
    #pragma unroll
    for (int o = 1; o < 64; o <<= 1) {
        int y = __shfl_up(x, o);
        if (j >= o) x += y;
    }
    offs[j] = x - c;
    if (j == 63) offs[64] = x;
    off[b * (NB_ + 1) + j] = x - c;
    if (j == 63) off[b * (NB_ + 1) + 64] = x;
    __syncthreads();
    for (int jj = 0; jj < NB_; ++jj) {
        int o = offs[jj];
        int c2 = offs[jj + 1] - o;
        const int* lst = idxl + ((size_t)(b * NB_ + jj)) * S_;
        for (int k = j; k < c2; k += 64) {
            perm[(size_t)b * S_ + o + k] = lst[k];
            p2b[(size_t)b * S_ + o + k] = jj;
        }
    }
}

// ---------------- fused per-row: Z (segment sums) -> w -> Eh *= (W - w[p2b[t]]) ----------------
__global__ __launch_bounds__(256) void zwgamma_kernel(
    unsigned short* __restrict__ Eh, const int* __restrict__ p2b,
    const int* __restrict__ off, const int* __restrict__ cnt,
    const int* __restrict__ bucket, const float* __restrict__ Mrow)
{
    int row = blockIdx.x;            // 0..ROWS-1
    int b = row >> 11;
    __shared__ float er[S_];         // 8KB
    __shared__ float zl[NB_];
    __shared__ float wl[NB_ + 1];
    int tid = threadIdx.x;
    unsigned short* Er = Eh + (size_t)row * S_;
    int t0 = tid * 8;
    s16x8 ev = *(const s16x8*)(Er + t0);
    #pragma unroll
    for (int i = 0; i < 8; ++i)
        er[t0 + i] = b2f((unsigned short)ev[i]);
    __syncthreads();
    {
        int j = tid >> 2, sub = tid & 3;
        int lo = off[b * (NB_ + 1) + j], hiX = off[b * (NB_ + 1) + j + 1];
        float z = 0.f;
        for (int k = lo + sub; k < hiX; k += 4) z += er[k];
        z += __shfl_xor(z, 1);
        z += __shfl_xor(z, 2);
        if (sub == 0) zl[j] = z;
    }
    __syncthreads();
    if (tid < NB_) {
        int j = tid;
        float zj = zl[j];
        float ztot = zj;
        #pragma unroll
        for (int o = 32; o; o >>= 1) ztot += __shfl_xor(ztot, o);
        int bs = bucket[row];
        float em = __expf(-Mrow[row]);
        float wj = 0.f;
        if (j != bs) wj = 1.0f / (ztot - zj + (float)cnt[b * NB_ + j] * em);
        float Wt = wj;
        #pragma unroll
        for (int o = 32; o; o >>= 1) Wt += __shfl_xor(Wt, o);
        wl[j] = wj;
        if (j == 0) wl[NB_] = Wt;
    }
    __syncthreads();
    float Wt = wl[NB_];
    const int* pb = p2b + (size_t)b * S_ + t0;
    int4 b0 = *(const int4*)pb;
    int4 b1 = *(const int4*)(pb + 4);
    s16x8 ov;
    ov[0] = (short)f2b(er[t0 + 0] * (Wt - wl[b0.x]));
    ov[1] = (short)f2b(er[t0 + 1] * (Wt - wl[b0.y]));
    ov[2] = (short)f2b(er[t0 + 2] * (Wt - wl[b0.z]));
    ov[3] = (short)f2b(er[t0 + 3] * (Wt - wl[b0.w]));
    ov[4] = (short)f2b(er[t0 + 4] * (Wt - wl[b1.x]));
    ov[5] = (short)f2b(er[t0 + 5] * (Wt - wl[b1.y]));
    ov[6] = (short)f2b(er[t0 + 6] * (Wt - wl[b1.z]));
    ov[7] = (short)f2b(er[t0 + 7] * (Wt - wl[b1.w]));
    *(s16x8*)(Er + t0) = ov;
}

extern "C" void kernel_launch(void* const* d_in, const int* in_sizes, int n_in,
                              void* d_out, int out_size, void* d_ws, size_t ws_size,
                              hipStream_t stream) {
    (void)in_sizes; (void)n_in; (void)out_size; (void)ws_size;
    const float* x  = (const float*)d_in[0];
    const float* Wq = (const float*)d_in[1];
    const float* bq = (const float*)d_in[2];
    const float* Wv = (const float*)d_in[3];
    const float* bv = (const float*)d_in[4];
    const float* H  = (const float*)d_in[5];
    float* out = (float*)d_out;

    char* p = (char*)d_ws;
    auto alloc = [&](size_t bytes) -> char* {
        char* r = p; p += (bytes + 255) & ~(size_t)255; return r;
    };
    float* v       = (float*)alloc((size_t)ROWS * D_ * 4);
    float* Mrow    = (float*)alloc((size_t)ROWS * 4);
    float* sumVb   = (float*)alloc((size_t)B_ * NB_ * D_ * 4);
    float* sumVall = (float*)alloc((size_t)B_ * D_ * 4);
    int*   bucket  = (int*)alloc((size_t)ROWS * 4);
    int*   cnt     = (int*)alloc((size_t)B_ * NB_ * 4);
    int*   offb    = (int*)alloc((size_t)B_ * (NB_ + 1) * 4);
    int*   perm    = (int*)alloc((size_t)B_ * S_ * 4);
    int*   p2b     = (int*)alloc((size_t)B_ * S_ * 4);
    int*   idxl    = (int*)alloc((size_t)B_ * NB_ * S_ * 4);
    unsigned short* xh   = (unsigned short*)alloc((size_t)ROWS * D_ * 2);
    unsigned short* qh   = (unsigned short*)alloc((size_t)ROWS * D_ * 2);
    unsigned short* Wqvh = (unsigned short*)alloc((size_t)2 * D_ * D_ * 2);
    unsigned short* vTh  = (unsigned short*)alloc((size_t)B_ * D_ * S_ * 2);
    unsigned short* Eh   = (unsigned short*)alloc((size_t)B_ * S_ * S_ * 2);

    // 1. prep: zeros + bf16 converts
    prep_kernel<<<2048, 256, 0, stream>>>(x, xh, Wq, Wv, Wqvh, Mrow, cnt, sumVall);
    // 2. fused q|v projection
    mfma_proj<<<dim3(2 * D_ / 64, ROWS / 128, 1), 256, 0, stream>>>(
        xh, Wqvh, bq, bv, Mrow, qh, v);
    // 3. buckets + hist + M finalize
    bucket_kernel<<<ROWS, 64, 0, stream>>>(qh, H, bucket, Mrow, cnt, idxl);
    // 4. prefix + perm/p2b (cooperative fill)
    permprefix_kernel<<<B_, 64, 0, stream>>>(cnt, idxl, offb, perm, p2b);
    // 5. merged: vT transpose (permuted) + per-bucket sumV
    vprep_kernel<<<2048 + 256, 256, 0, stream>>>(v, perm, vTh, cnt, idxl, sumVb, sumVall);
    // 6. Eh = bf16(exp(qh . qh[perm[t']] * scale - M)), 128x128 tiles
    mfma_qk<<<dim3(S_ / 128, S_ / 128, B_), 256, 0, stream>>>(qh, perm, Mrow, Eh);
    // 7. Z -> w -> gamma, fused per row, Eh in place
    zwgamma_kernel<<<ROWS, 256, 0, stream>>>(Eh, p2b, offb, cnt, bucket, Mrow);
    // 8. out = E' vT^T + rowterm, BK=128
    mfma_pv64<<<dim3(D_ / 64, S_ / 64, B_), 256, 0, stream>>>(
        Eh, vTh, sumVall, sumVb, bucket, out);
}

// Round 11
// 106.520 us; speedup vs baseline: 1.1905x; 1.1905x over previous
//
#include <hip/hip_runtime.h>
#include <math.h>

#define B_ 2
#define S_ 2048
#define D_ 512
#define NB_ 64
#define NH_ 6
#define ROWS (B_*S_)           // 4096
#define SCALE 0.044194173824159216f   // 1/sqrt(512)

typedef float f32x4 __attribute__((ext_vector_type(4)));
typedef __bf16 bf16v8 __attribute__((ext_vector_type(8)));
typedef short s16x8 __attribute__((ext_vector_type(8)));
typedef unsigned short u16x4 __attribute__((ext_vector_type(4)));

__device__ __forceinline__ float b2f(unsigned short u) {
    unsigned int v = (unsigned int)u << 16;
    float f; __builtin_memcpy(&f, &v, 4); return f;
}
__device__ __forceinline__ unsigned short f2b(float f) {
    unsigned int v; __builtin_memcpy(&v, &f, 4);
    v += 0x7fffu + ((v >> 16) & 1u);      // RNE
    return (unsigned short)(v >> 16);
}

#define GLOAD16(g, l) __builtin_amdgcn_global_load_lds( \
    (const __attribute__((address_space(1))) unsigned int*)(g), \
    (__attribute__((address_space(3))) unsigned int*)(uintptr_t)(l), 16, 0, 0)

// ---------------- prep: zeros + f32->bf16 converts ----------------
__global__ void prep_kernel(
    const float* __restrict__ x, unsigned short* __restrict__ xh,
    const float* __restrict__ Wq, const float* __restrict__ Wv,
    unsigned short* __restrict__ Wqvh,
    float* __restrict__ Mrow, int* __restrict__ cnt, float* __restrict__ sumVall)
{
    int t = blockIdx.x * 256 + threadIdx.x;
    int stride = gridDim.x * 256;
    for (int i = t; i < ROWS * D_ / 4; i += stride) {
        float4 f = ((const float4*)x)[i];
        u16x4 u = { f2b(f.x), f2b(f.y), f2b(f.z), f2b(f.w) };
        ((u16x4*)xh)[i] = u;
    }
    for (int i = t; i < D_ * D_ / 4; i += stride) {
        float4 f = ((const float4*)Wq)[i];
        u16x4 u = { f2b(f.x), f2b(f.y), f2b(f.z), f2b(f.w) };
        ((u16x4*)Wqvh)[i] = u;
        float4 g = ((const float4*)Wv)[i];
        u16x4 w = { f2b(g.x), f2b(g.y), f2b(g.z), f2b(g.w) };
        ((u16x4*)(Wqvh + (size_t)D_ * D_))[i] = w;
    }
    for (int i = t; i < ROWS; i += stride) Mrow[i] = 0.f;
    for (int i = t; i < B_ * NB_; i += stride) cnt[i] = 0;
    for (int i = t; i < B_ * D_; i += stride) sumVall[i] = 0.f;
}

// ---------------- fused q|v projection, tile 128x64x64, N=1024 ----------------
__global__ __launch_bounds__(256) void mfma_proj(
    const unsigned short* __restrict__ A, const unsigned short* __restrict__ B,
    const float* __restrict__ bq, const float* __restrict__ bv,
    float* __restrict__ MrowRaw, unsigned short* __restrict__ qh,
    float* __restrict__ v)
{
    __shared__ unsigned short Als[128 * 64];   // 16KB
    __shared__ unsigned short Bls[64 * 64];    // 8KB
    const int K = D_;
    int tid = threadIdx.x;
    int w = tid >> 6, l = tid & 63;
    int wr = w >> 1, wc = w & 1;

    int gx = gridDim.x;
    int nwg = gx * gridDim.y;
    int lin = blockIdx.y * gx + blockIdx.x;
    int qq = nwg >> 3;
    int wg = (lin & 7) * qq + (lin >> 3);
    int m0 = (wg / gx) * 128, n0 = (wg % gx) * 64;

    const unsigned short* asrc[4];
    #pragma unroll
    for (int j = 0; j < 4; ++j) {
        int chunk = w * 4 + j;
        int r = chunk * 8 + (l >> 3);
        asrc[j] = A + (size_t)(m0 + r) * K + ((l & 7) ^ (l >> 3)) * 8;
    }
    const unsigned short* bsrc[2];
    #pragma unroll
    for (int j = 0; j < 2; ++j) {
        int chunk = w * 2 + j;
        int r = n0 + chunk * 8 + (l >> 3);
        bsrc[j] = B + (size_t)r * K + ((l & 7) ^ (l >> 3)) * 8;
    }

    f32x4 acc[4][2] = {};
    int rl = l & 15, hi = l >> 4;

    for (int k0 = 0; k0 < K; k0 += 64) {
        #pragma unroll
        for (int j = 0; j < 4; ++j) GLOAD16(asrc[j] + k0, Als + (w * 4 + j) * 512);
        #pragma unroll
        for (int j = 0; j < 2; ++j) GLOAD16(bsrc[j] + k0, Bls + (w * 2 + j) * 512);
        __syncthreads();
        bf16v8 af[4][2], bfr[2][2];
        const char* Ab = (const char*)Als;
        const char* Bb = (const char*)Bls;
        #pragma unroll
        for (int kk = 0; kk < 2; ++kk) {
            int kb = kk * 64 + hi * 16;
            #pragma unroll
            for (int f = 0; f < 4; ++f) {
                int ra = wr * 64 + f * 16 + rl;
                af[f][kk] = *(const bf16v8*)(Ab + ra * 128 + (kb ^ ((ra & 7) << 4)));
            }
            #pragma unroll
            for (int f = 0; f < 2; ++f) {
                int rb = wc * 32 + f * 16 + rl;
                bfr[f][kk] = *(const bf16v8*)(Bb + rb * 128 + (kb ^ ((rb & 7) << 4)));
            }
        }
        #pragma unroll
        for (int fm = 0; fm < 4; ++fm)
            #pragma unroll
            for (int fn = 0; fn < 2; ++fn)
                #pragma unroll
                for (int kk = 0; kk < 2; ++kk)
                    acc[fm][fn] = __builtin_amdgcn_mfma_f32_16x16x32_bf16(
                        af[fm][kk], bfr[fn][kk], acc[fm][fn], 0, 0, 0);
        __syncthreads();
    }

    int colBase = n0 + wc * 32;
    if (colBase < D_) {
        #pragma unroll
        for (int fm = 0; fm < 4; ++fm) {
            float p[4] = {0.f, 0.f, 0.f, 0.f};
            #pragma unroll
            for (int fn = 0; fn < 2; ++fn) {
                int col = colBase + fn * 16 + rl;
                float bs = bq[col];
                #pragma unroll
                for (int r = 0; r < 4; ++r) {
                    int row = m0 + wr * 64 + fm * 16 + hi * 4 + r;
                    float cv = acc[fm][fn][r] + bs;
                    unsigned short h = f2b(cv);
                    qh[(size_t)row * D_ + col] = h;
                    float qb = b2f(h);
                    p[r] = fmaf(qb, qb, p[r]);
                }
            }
            #pragma unroll
            for (int mask = 1; mask < 16; mask <<= 1)
                #pragma unroll
                for (int r = 0; r < 4; ++r) p[r] += __shfl_xor(p[r], mask);
            if (rl == 0) {
                #pragma unroll
                for (int r = 0; r < 4; ++r) {
                    int row = m0 + wr * 64 + fm * 16 + hi * 4 + r;
                    atomicAdd(&MrowRaw[row], p[r]);
                }
            }
        }
    } else {
        #pragma unroll
        for (int fm = 0; fm < 4; ++fm)
            #pragma unroll
            for (int fn = 0; fn < 2; ++fn) {
                int col = colBase + fn * 16 + rl - D_;
                float bs = bv[col];
                #pragma unroll
                for (int r = 0; r < 4; ++r) {
                    int row = m0 + wr * 64 + fm * 16 + hi * 4 + r;
                    v[(size_t)row * D_ + col] = acc[fm][fn][r] + bs;
                }
            }
    }
}

// ---------------- QK^T, 128x128x64 tile, exp epilogue, perm on B ----------------
__global__ __launch_bounds__(256) void mfma_qk(
    const unsigned short* __restrict__ qh, const int* __restrict__ prm,
    const float* __restrict__ Mrow, unsigned short* __restrict__ Eh)
{
    __shared__ unsigned short Als[128 * 64];   // 16KB
    __shared__ unsigned short Bls[128 * 64];   // 16KB
    const int K = D_;
    int tid = threadIdx.x;
    int w = tid >> 6, l = tid & 63;
    int wr = w >> 1, wc = w & 1;
    int zb = blockIdx.z;
    const unsigned short* A = qh + (size_t)zb * S_ * D_;
    prm += (size_t)zb * S_;
    const float* Mb = Mrow + (size_t)zb * S_;
    unsigned short* Eb = Eh + (size_t)zb * S_ * S_;

    int gx = gridDim.x;
    int nwg = gx * gridDim.y;
    int lin = blockIdx.y * gx + blockIdx.x;
    int qq = nwg >> 3;
    int wg = (lin & 7) * qq + (lin >> 3);
    int m0 = (wg / gx) * 128, n0 = (wg % gx) * 128;

    const unsigned short* asrc[4];
    const unsigned short* bsrc[4];
    #pragma unroll
    for (int j = 0; j < 4; ++j) {
        int chunk = w * 4 + j;
        int r = chunk * 8 + (l >> 3);
        int c = ((l & 7) ^ (l >> 3)) * 8;
        asrc[j] = A + (size_t)(m0 + r) * K + c;
        bsrc[j] = A + (size_t)prm[n0 + r] * K + c;
    }

    f32x4 acc[4][4] = {};
    int rl = l & 15, hi = l >> 4;

    for (int k0 = 0; k0 < K; k0 += 64) {
        #pragma unroll
        for (int j = 0; j < 4; ++j) GLOAD16(asrc[j] + k0, Als + (w * 4 + j) * 512);
        #pragma unroll
        for (int j = 0; j < 4; ++j) GLOAD16(bsrc[j] + k0, Bls + (w * 4 + j) * 512);
        __syncthreads();
        bf16v8 af[4][2], bfr[4][2];
        const char* Ab = (const char*)Als;
        const char* Bb = (const char*)Bls;
        #pragma unroll
        for (int kk = 0; kk < 2; ++kk) {
            int kb = kk * 64 + hi * 16;
            #pragma unroll
            for (int f = 0; f < 4; ++f) {
                int ra = wr * 64 + f * 16 + rl;
                af[f][kk] = *(const bf16v8*)(Ab + ra * 128 + (kb ^ ((ra & 7) << 4)));
                int rb = wc * 64 + f * 16 + rl;
                bfr[f][kk] = *(const bf16v8*)(Bb + rb * 128 + (kb ^ ((rb & 7) << 4)));
            }
        }
        #pragma unroll
        for (int fm = 0; fm < 4; ++fm)
            #pragma unroll
            for (int fn = 0; fn < 4; ++fn)
                #pragma unroll
                for (int kk = 0; kk < 2; ++kk)
                    acc[fm][fn] = __builtin_amdgcn_mfma_f32_16x16x32_bf16(
                        af[fm][kk], bfr[fn][kk], acc[fm][fn], 0, 0, 0);
        __syncthreads();
    }

    #pragma unroll
    for (int fm = 0; fm < 4; ++fm) {
        #pragma unroll
        for (int r = 0; r < 4; ++r) {
            int row = m0 + wr * 64 + fm * 16 + hi * 4 + r;
            float m = Mb[row];
            #pragma unroll
            for (int fn = 0; fn < 4; ++fn) {
                int col = n0 + wc * 64 + fn * 16 + rl;
                float ev = __expf(fmaf(acc[fm][fn][r], SCALE, -m));
                Eb[(size_t)row * S_ + col] = f2b(ev);
            }
        }
    }
}

// ---------------- PV GEMM: out = E' vT^T + rowterm. tile 64x64x64, 4 waves ----------------
// grid (8, 32, B): m-panel-grouped XCD mapping
__global__ __launch_bounds__(256) void mfma_pv64(
    const unsigned short* __restrict__ Eh, const unsigned short* __restrict__ vT,
    const float* __restrict__ sumVall, const float* __restrict__ sumVb,
    const int* __restrict__ bucket, float* __restrict__ out)
{
    __shared__ unsigned short Als[64 * 64];   // 8KB
    __shared__ unsigned short Bls[64 * 64];   // 8KB
    int tid = threadIdx.x, w = tid >> 6, l = tid & 63;
    int wr = w >> 1, wc = w & 1, rl = l & 15, hi = l >> 4;
    int zb = blockIdx.z;
    const unsigned short* A  = Eh + (size_t)zb * S_ * S_;
    const unsigned short* Bv = vT + (size_t)zb * D_ * S_;
    const float* sva = sumVall + (size_t)zb * D_;
    const float* svb = sumVb + (size_t)zb * NB_ * D_;
    const int* bkt = bucket + (size_t)zb * S_;
    float* outb = out + (size_t)zb * S_ * D_;

    int lin = blockIdx.y * 8 + blockIdx.x;    // 0..255
    int xcd = lin & 7, rest = lin >> 3;
    int m0 = (((rest >> 3) << 3) | xcd) * 64;
    int n0 = (rest & 7) * 64;

    const unsigned short* asrc[2];
    const unsigned short* bsrc[2];
    #pragma unroll
    for (int j = 0; j < 2; ++j) {
        int chunk = w * 2 + j;
        int r = chunk * 8 + (l >> 3);
        int c = ((l & 7) ^ (l >> 3)) * 8;
        asrc[j] = A  + (size_t)(m0 + r) * S_ + c;
        bsrc[j] = Bv + (size_t)(n0 + r) * S_ + c;
    }

    f32x4 acc[2][2] = {};
    for (int k0 = 0; k0 < S_; k0 += 64) {
        #pragma unroll
        for (int j = 0; j < 2; ++j) GLOAD16(asrc[j] + k0, Als + (w * 2 + j) * 512);
        #pragma unroll
        for (int j = 0; j < 2; ++j) GLOAD16(bsrc[j] + k0, Bls + (w * 2 + j) * 512);
        __syncthreads();
        bf16v8 af[2][2], bfr[2][2];
        const char* Ab = (const char*)Als;
        const char* Bb = (const char*)Bls;
        #pragma unroll
        for (int kk = 0; kk < 2; ++kk) {
            int kb = kk * 64 + hi * 16;
            #pragma unroll
            for (int f = 0; f < 2; ++f) {
                int ra = wr * 32 + f * 16 + rl;
                af[f][kk] = *(const bf16v8*)(Ab + ra * 128 + (kb ^ ((ra & 7) << 4)));
                int rb = wc * 32 + f * 16 + rl;
                bfr[f][kk] = *(const bf16v8*)(Bb + rb * 128 + (kb ^ ((rb & 7) << 4)));
            }
        }
        #pragma unroll
        for (int fm = 0; fm < 2; ++fm)
            #pragma unroll
            for (int fn = 0; fn < 2; ++fn)
                #pragma unroll
                for (int kk = 0; kk < 2; ++kk)
                    acc[fm][fn] = __builtin_amdgcn_mfma_f32_16x16x32_bf16(
                        af[fm][kk], bfr[fn][kk], acc[fm][fn], 0, 0, 0);
        __syncthreads();
    }
    const float invS = 1.0f / (float)S_;
    #pragma unroll
    for (int fm = 0; fm < 2; ++fm)
        #pragma unroll
        for (int fn = 0; fn < 2; ++fn) {
            int col = n0 + wc * 32 + fn * 16 + rl;
            float sa = sva[col];
            #pragma unroll
            for (int r = 0; r < 4; ++r) {
                int row = m0 + wr * 32 + fm * 16 + hi * 4 + r;
                int bm = bkt[row];
                outb[(size_t)row * D_ + col] =
                    acc[fm][fn][r] + (sa - svb[(size_t)bm * D_ + col]) * invS;
            }
        }
}

// ---------------- merged: transpose_v (blocks 0..2047) + sumv2 (blocks 2048..2303) ----------------
__global__ __launch_bounds__(256) void vprep_kernel(
    const float* __restrict__ v, const int* __restrict__ perm,
    unsigned short* __restrict__ vT,
    const int* __restrict__ cnt, const int* __restrict__ idxl,
    float* __restrict__ sumVb, float* __restrict__ sumVall)
{
    int bid = blockIdx.x;
    if (bid < 2048) {
        __shared__ float tl[32][33];
        int b = bid >> 10;
        int r = bid & 1023;
        int d0 = (r & 15) * 32, s0 = (r >> 4) * 32;
        int tx = threadIdx.x & 31, ty = threadIdx.x >> 5;
        const float* vb = v + (size_t)b * S_ * D_;
        const int* pm = perm + (size_t)b * S_;
        #pragma unroll
        for (int i = 0; i < 4; ++i)
            tl[ty + i * 8][tx] = vb[(size_t)pm[s0 + ty + i * 8] * D_ + d0 + tx];
        __syncthreads();
        unsigned short* vt = vT + (size_t)b * D_ * S_;
        #pragma unroll
        for (int i = 0; i < 4; ++i)
            vt[(size_t)(d0 + ty + i * 8) * S_ + s0 + tx] = f2b(tl[tx][ty + i * 8]);
    } else {
        int sid = bid - 2048;
        int j = sid & 63, b = (sid >> 6) & 1, dblk = sid >> 7;
        int d = dblk * 256 + threadIdx.x;
        int n = cnt[b * NB_ + j];
        const int* lst = idxl + ((size_t)(b * NB_ + j)) * S_;
        const float* vb = v + (size_t)b * S_ * D_;
        float acc = 0.f;
        for (int k = 0; k < n; ++k)
            acc += vb[(size_t)lst[k] * D_ + d];
        sumVb[((size_t)b * NB_ + j) * D_ + d] = acc;
        atomicAdd(&sumVall[b * D_ + d], acc);
    }
}

// ---------------- buckets from qh + hist; finalize Mrow ----------------
__global__ __launch_bounds__(64) void bucket_kernel(
    const unsigned short* __restrict__ qh, const float* __restrict__ H,
    int* __restrict__ bucket, float* __restrict__ Mrow,
    int* __restrict__ cnt, int* __restrict__ idxl)
{
    int row = blockIdx.x;
    int lane = threadIdx.x;
    const unsigned short* qr = qh + (size_t)row * D_;
    float proj[NH_] = {};
    s16x8 qv8 = *(const s16x8*)(qr + lane * 8);
    #pragma unroll
    for (int i = 0; i < 8; ++i) {
        float qv = b2f((unsigned short)qv8[i]);
        int d = lane * 8 + i;
        #pragma unroll
        for (int n = 0; n < NH_; ++n)
            proj[n] = fmaf(qv, H[d * NH_ + n], proj[n]);
    }
    #pragma unroll
    for (int off = 32; off; off >>= 1) {
        #pragma unroll
        for (int n = 0; n < NH_; ++n) proj[n] += __shfl_down(proj[n], off);
    }
    if (lane == 0) {
        int bk = 0;
        #pragma unroll
        for (int n = 0; n < NH_; ++n) {
            float p = proj[n] + H[D_ * NH_ + n];
            if (p >= 0.f) bk |= (1 << n);
        }
        bucket[row] = bk;
        Mrow[row] = Mrow[row] * SCALE;
        int b = row >> 11, s = row & (S_ - 1);
        int pos = atomicAdd(&cnt[b * NB_ + bk], 1);
        idxl[((size_t)(b * NB_ + bk)) * S_ + pos] = s;
    }
}

// ---------------- prefix sum + perm/p2b build, 256 threads (4 per bucket) ----------------
__global__ __launch_bounds__(256) void permprefix_kernel(
    const int* __restrict__ cnt, const int* __restrict__ idxl,
    int* __restrict__ off, int* __restrict__ perm, int* __restrict__ p2b)
{
    int b = blockIdx.x;
    int tid = threadIdx.x;
    __shared__ int offs[NB_ + 1];
    if (tid < 64) {
        int c = cnt[b * NB_ + tid];
        int x = c;
        #pragma unroll
        for (int o = 1; o < 64; o <<= 1) {
            int y = __shfl_up(x, o);
            if (tid >= o) x += y;
        }
        offs[tid] = x - c;
        off[b * (NB_ + 1) + tid] = x - c;
        if (tid == 63) { offs[64] = x; off[b * (NB_ + 1) + 64] = x; }
    }
    __syncthreads();
    int j = tid >> 2, sub = tid & 3;
    int o = offs[j];
    int c2 = offs[j + 1] - o;
    const int* lst = idxl + ((size_t)(b * NB_ + j)) * S_;
    for (int k = sub; k < c2; k += 4) {
        perm[(size_t)b * S_ + o + k] = lst[k];
        p2b[(size_t)b * S_ + o + k] = j;
    }
}

// ---------------- fused per-row: Z (segment sums) -> w -> Eh *= (W - w[p2b[t]]) ----------------
__global__ __launch_bounds__(256) void zwgamma_kernel(
    unsigned short* __restrict__ Eh, const int* __restrict__ p2b,
    const int* __restrict__ off, const int* __restrict__ cnt,
    const int* __restrict__ bucket, const float* __restrict__ Mrow)
{
    int row = blockIdx.x;            // 0..ROWS-1
    int b = row >> 11;
    __shared__ float er[S_];         // 8KB
    __shared__ float zl[NB_];
    __shared__ float wl[NB_ + 1];
    int tid = threadIdx.x;
    unsigned short* Er = Eh + (size_t)row * S_;
    int t0 = tid * 8;
    s16x8 ev = *(const s16x8*)(Er + t0);
    #pragma unroll
    for (int i = 0; i < 8; ++i)
        er[t0 + i] = b2f((unsigned short)ev[i]);
    __syncthreads();
    {
        int j = tid >> 2, sub = tid & 3;
        int lo = off[b * (NB_ + 1) + j], hiX = off[b * (NB_ + 1) + j + 1];
        float z = 0.f;
        for (int k = lo + sub; k < hiX; k += 4) z += er[k];
        z += __shfl_xor(z, 1);
        z += __shfl_xor(z, 2);
        if (sub == 0) zl[j] = z;
    }
    __syncthreads();
    if (tid < NB_) {
        int j = tid;
        float zj = zl[j];
        float ztot = zj;
        #pragma unroll
        for (int o = 32; o; o >>= 1) ztot += __shfl_xor(ztot, o);
        int bs = bucket[row];
        float em = __expf(-Mrow[row]);
        float wj = 0.f;
        if (j != bs) wj = 1.0f / (ztot - zj + (float)cnt[b * NB_ + j] * em);
        float Wt = wj;
        #pragma unroll
        for (int o = 32; o; o >>= 1) Wt += __shfl_xor(Wt, o);
        wl[j] = wj;
        if (j == 0) wl[NB_] = Wt;
    }
    __syncthreads();
    float Wt = wl[NB_];
    const int* pb = p2b + (size_t)b * S_ + t0;
    int4 b0 = *(const int4*)pb;
    int4 b1 = *(const int4*)(pb + 4);
    s16x8 ov;
    ov[0] = (short)f2b(er[t0 + 0] * (Wt - wl[b0.x]));
    ov[1] = (short)f2b(er[t0 + 1] * (Wt - wl[b0.y]));
    ov[2] = (short)f2b(er[t0 + 2] * (Wt - wl[b0.z]));
    ov[3] = (short)f2b(er[t0 + 3] * (Wt - wl[b0.w]));
    ov[4] = (short)f2b(er[t0 + 4] * (Wt - wl[b1.x]));
    ov[5] = (short)f2b(er[t0 + 5] * (Wt - wl[b1.y]));
    ov[6] = (short)f2b(er[t0 + 6] * (Wt - wl[b1.z]));
    ov[7] = (short)f2b(er[t0 + 7] * (Wt - wl[b1.w]));
    *(s16x8*)(Er + t0) = ov;
}

extern "C" void kernel_launch(void* const* d_in, const int* in_sizes, int n_in,
                              void* d_out, int out_size, void* d_ws, size_t ws_size,
                              hipStream_t stream) {
    (void)in_sizes; (void)n_in; (void)out_size; (void)ws_size;
    const float* x  = (const float*)d_in[0];
    const float* Wq = (const float*)d_in[1];
    const float* bq = (const float*)d_in[2];
    const float* Wv = (const float*)d_in[3];
    const float* bv = (const float*)d_in[4];
    const float* H  = (const float*)d_in[5];
    float* out = (float*)d_out;

    char* p = (char*)d_ws;
    auto alloc = [&](size_t bytes) -> char* {
        char* r = p; p += (bytes + 255) & ~(size_t)255; return r;
    };
    float* v       = (float*)alloc((size_t)ROWS * D_ * 4);
    float* Mrow    = (float*)alloc((size_t)ROWS * 4);
    float* sumVb   = (float*)alloc((size_t)B_ * NB_ * D_ * 4);
    float* sumVall = (float*)alloc((size_t)B_ * D_ * 4);
    int*   bucket  = (int*)alloc((size_t)ROWS * 4);
    int*   cnt     = (int*)alloc((size_t)B_ * NB_ * 4);
    int*   offb    = (int*)alloc((size_t)B_ * (NB_ + 1) * 4);
    int*   perm    = (int*)alloc((size_t)B_ * S_ * 4);
    int*   p2b     = (int*)alloc((size_t)B_ * S_ * 4);
    int*   idxl    = (int*)alloc((size_t)B_ * NB_ * S_ * 4);
    unsigned short* xh   = (unsigned short*)alloc((size_t)ROWS * D_ * 2);
    unsigned short* qh   = (unsigned short*)alloc((size_t)ROWS * D_ * 2);
    unsigned short* Wqvh = (unsigned short*)alloc((size_t)2 * D_ * D_ * 2);
    unsigned short* vTh  = (unsigned short*)alloc((size_t)B_ * D_ * S_ * 2);
    unsigned short* Eh   = (unsigned short*)alloc((size_t)B_ * S_ * S_ * 2);

    // 1. prep: zeros + bf16 converts
    prep_kernel<<<2048, 256, 0, stream>>>(x, xh, Wq, Wv, Wqvh, Mrow, cnt, sumVall);
    // 2. fused q|v projection
    mfma_proj<<<dim3(2 * D_ / 64, ROWS / 128, 1), 256, 0, stream>>>(
        xh, Wqvh, bq, bv, Mrow, qh, v);
    // 3. buckets + hist + M finalize
    bucket_kernel<<<ROWS, 64, 0, stream>>>(qh, H, bucket, Mrow, cnt, idxl);
    // 4. prefix + perm/p2b (256 threads, 4 per bucket)
    permprefix_kernel<<<B_, 256, 0, stream>>>(cnt, idxl, offb, perm, p2b);
    // 5. merged: vT transpose (permuted) + per-bucket sumV
    vprep_kernel<<<2048 + 256, 256, 0, stream>>>(v, perm, vTh, cnt, idxl, sumVb, sumVall);
    // 6. Eh = bf16(exp(qh . qh[perm[t']] * scale - M)), 128x128 tiles
    mfma_qk<<<dim3(S_ / 128, S_ / 128, B_), 256, 0, stream>>>(qh, perm, Mrow, Eh);
    // 7. Z -> w -> gamma, fused per row, Eh in place
    zwgamma_kernel<<<ROWS, 256, 0, stream>>>(Eh, p2b, offb, cnt, bucket, Mrow);
    // 8. out = E' vT^T + rowterm (64x64x64, 512 blocks)
    mfma_pv64<<<dim3(D_ / 64, S_ / 64, B_), 256, 0, stream>>>(
        Eh, vTh, sumVall, sumVb, bucket, out);
}